// Round 5
// baseline (272.963 us; speedup 1.0000x reference)
//
#include <hip/hip_runtime.h>

#define Bn 4
#define Qn 128
#define Kn 1024
#define Dn 512   // DQ = DK = DV = 512
#define Hn 256
#define SCALE 2.8853900817779268f   // 2*log2(e): pre-scale proj so tanh uses exp2
#define LOG2E 1.4426950408889634f

// ---------------------------------------------------------------------------
// Kernel 1: projections. 128 threads/block, B (weights) streamed from L1
// (no LDS), A staged transposed in LDS with permuted rows (write = 2-way
// conflict = free; read = ds_read_b128). Outputs pre-scaled by 2*log2e.
//   blocks 0..63   : queries@Wq, tile 32m x 64n, full D, thread 2m x 8n
//   blocks 64..575 : keys@Wk,    tile 64m x 64n, D-half (split-k 2), 4m x 8n,
//                    partials to kpart0/kpart1 (summed in score staging)
// LDS row r of s_a holds original k-index 4*(r&15)+(r>>4) (perm makes the
// b32 transpose-writes hit 64 distinct (4*c4+row) -> 2-way, free).
// ---------------------------------------------------------------------------
__global__ __launch_bounds__(128) void proj_kernel(
    const float* __restrict__ queries, const float* __restrict__ keys,
    const float* __restrict__ Wq, const float* __restrict__ Wk,
    const int* __restrict__ valid_lens,
    float* __restrict__ qproj, float* __restrict__ kpart0,
    float* __restrict__ kpart1)
{
    const int blk = blockIdx.x;
    const int t = threadIdx.x;
    __shared__ float s_a[64][68];       // 17.4 KB (q-type uses rows [0..63], m<32)

    if (blk < 64) {
        // ---------------- q-type ----------------
        const int nt = blk & 3, mtq = blk >> 2;
        const int m0 = mtq * 32, n0 = nt * 64;
        const int trow = t >> 3, tcol = t & 7;      // 16 x 8 -> 32m x 64n
        const float* Wb = Wq + n0 + tcol * 8;
        float acc[2][8];
        #pragma unroll
        for (int i = 0; i < 2; ++i)
            #pragma unroll
            for (int j = 0; j < 8; ++j) acc[i][j] = 0.f;

        float4 ra[4];
        #pragma unroll
        for (int i = 0; i < 4; ++i) {               // preload kt=0: 32r x 16c4
            int idx = t + i * 128, r = idx >> 4, cc = idx & 15;
            ra[i] = *(const float4*)(queries + (size_t)(m0 + r) * Dn + cc * 4);
        }
        for (int kt = 0; kt < 8; ++kt) {
            __syncthreads();
            #pragma unroll
            for (int i = 0; i < 4; ++i) {           // transpose to perm rows
                int idx = t + i * 128, r = idx >> 4, cc = idx & 15;
                s_a[cc +  0][r] = ra[i].x;
                s_a[cc + 16][r] = ra[i].y;
                s_a[cc + 32][r] = ra[i].z;
                s_a[cc + 48][r] = ra[i].w;
            }
            __syncthreads();
            if (kt < 7) {
                const int d0n = (kt + 1) * 64;
                #pragma unroll
                for (int i = 0; i < 4; ++i) {
                    int idx = t + i * 128, r = idx >> 4, cc = idx & 15;
                    ra[i] = *(const float4*)(queries + (size_t)(m0 + r) * Dn + d0n + cc * 4);
                }
            }
            #pragma unroll 16
            for (int r = 0; r < 64; ++r) {
                const int ko = 4 * (r & 15) + (r >> 4);     // original k of row r
                float2 a2 = *(const float2*)&s_a[r][trow * 2];
                const float* wb = Wb + (size_t)(kt * 64 + ko) * Hn;
                float4 b0 = *(const float4*)wb;
                float4 b1 = *(const float4*)(wb + 4);
                float bb[8] = {b0.x,b0.y,b0.z,b0.w,b1.x,b1.y,b1.z,b1.w};
                #pragma unroll
                for (int j = 0; j < 8; ++j) {
                    acc[0][j] += a2.x * bb[j];
                    acc[1][j] += a2.y * bb[j];
                }
            }
        }
        #pragma unroll
        for (int i = 0; i < 2; ++i) {
            float* dst = qproj + (size_t)(m0 + trow * 2 + i) * Hn + n0 + tcol * 8;
            float4 o0, o1;
            o0.x = acc[i][0]*SCALE; o0.y = acc[i][1]*SCALE;
            o0.z = acc[i][2]*SCALE; o0.w = acc[i][3]*SCALE;
            o1.x = acc[i][4]*SCALE; o1.y = acc[i][5]*SCALE;
            o1.z = acc[i][6]*SCALE; o1.w = acc[i][7]*SCALE;
            *(float4*)dst = o0; *(float4*)(dst + 4) = o1;
        }
    } else {
        // ---------------- k-type ----------------
        const int bk = blk - 64;                    // mt(64) | nt(4) | kc(2)
        const int kc = bk & 1, nt = (bk >> 1) & 3, mt = bk >> 3;
        const int m0 = mt * 64;                     // key row in [0,4096)
        if ((m0 & 1023) >= valid_lens[m0 >> 10]) return;
        const int n0 = nt * 64;
        const int trow = t >> 3, tcol = t & 7;      // 16 x 8 -> 64m x 64n (4m x 8n)
        const int dbase = kc * 256;
        const float* Wb = Wk + (size_t)dbase * Hn + n0 + tcol * 8;
        float* kpart = kc ? kpart1 : kpart0;
        float acc[4][8];
        #pragma unroll
        for (int i = 0; i < 4; ++i)
            #pragma unroll
            for (int j = 0; j < 8; ++j) acc[i][j] = 0.f;

        float4 ra[8];
        #pragma unroll
        for (int i = 0; i < 8; ++i) {               // preload kt=0: 64r x 16c4
            int idx = t + i * 128, r = idx >> 4, cc = idx & 15;
            ra[i] = *(const float4*)(keys + (size_t)(m0 + r) * Dn + dbase + cc * 4);
        }
        for (int kt = 0; kt < 4; ++kt) {
            __syncthreads();
            #pragma unroll
            for (int i = 0; i < 8; ++i) {
                int idx = t + i * 128, r = idx >> 4, cc = idx & 15;
                s_a[cc +  0][r] = ra[i].x;
                s_a[cc + 16][r] = ra[i].y;
                s_a[cc + 32][r] = ra[i].z;
                s_a[cc + 48][r] = ra[i].w;
            }
            __syncthreads();
            if (kt < 3) {
                const int d0n = dbase + (kt + 1) * 64;
                #pragma unroll
                for (int i = 0; i < 8; ++i) {
                    int idx = t + i * 128, r = idx >> 4, cc = idx & 15;
                    ra[i] = *(const float4*)(keys + (size_t)(m0 + r) * Dn + d0n + cc * 4);
                }
            }
            #pragma unroll 16
            for (int r = 0; r < 64; ++r) {
                const int ko = 4 * (r & 15) + (r >> 4);
                float4 a4 = *(const float4*)&s_a[r][trow * 4];
                const float* wb = Wb + (size_t)(kt * 64 + ko) * Hn;
                float4 b0 = *(const float4*)wb;
                float4 b1 = *(const float4*)(wb + 4);
                float aa[4] = {a4.x, a4.y, a4.z, a4.w};
                float bb[8] = {b0.x,b0.y,b0.z,b0.w,b1.x,b1.y,b1.z,b1.w};
                #pragma unroll
                for (int i = 0; i < 4; ++i)
                    #pragma unroll
                    for (int j = 0; j < 8; ++j)
                        acc[i][j] += aa[i] * bb[j];
            }
        }
        #pragma unroll
        for (int i = 0; i < 4; ++i) {
            float* dst = kpart + (size_t)(m0 + trow * 4 + i) * Hn + n0 + tcol * 8;
            float4 o0, o1;
            o0.x = acc[i][0]*SCALE; o0.y = acc[i][1]*SCALE;
            o0.z = acc[i][2]*SCALE; o0.w = acc[i][3]*SCALE;
            o1.x = acc[i][4]*SCALE; o1.y = acc[i][5]*SCALE;
            o1.z = acc[i][6]*SCALE; o1.w = acc[i][7]*SCALE;
            *(float4*)dst = o0; *(float4*)(dst + 4) = o1;
        }
    }
}

// ---------------------------------------------------------------------------
// Kernel 2: e = exp(score), max-free. Block = (b, 16q, 64k); wave = 4 q-rows.
// k staged transposed s_kT[h][k] (conflict-free b32 reads, the ONLY DS op in
// the loop; part0+part1 combined during staging). q-rows + wv read through
// wave-uniform scalar loads (SMEM pipe). tanh(x) = 1 - 2*rcp(1+exp2(x'))
// with x' pre-scaled by 2*log2e in proj. No cross-lane combine (lane owns
// full H for its k). Per-row expsum via butterfly + one atomic per wave.
// ---------------------------------------------------------------------------
__global__ __launch_bounds__(256) void score_kernel(
    const float* __restrict__ qproj, const float* __restrict__ kpart0,
    const float* __restrict__ kpart1, const float* __restrict__ wv,
    const int* __restrict__ valid_lens,
    float* __restrict__ escores, float* __restrict__ rowsum)
{
    const int blk = blockIdx.x;             // ((b*8 + qt)*16 + kt)
    const int kt = blk & 15;
    const int qt = (blk >> 4) & 7;
    const int b  = blk >> 7;
    const int vlen = valid_lens[b];
    const int k0 = kt * 64;
    if (k0 >= vlen) return;
    const int t = threadIdx.x;
    const int wave = __builtin_amdgcn_readfirstlane(t >> 6);
    const int lane = t & 63;

    __shared__ float s_kT[128][64];         // 32 KB, one h-half at a time

    const float* qb = qproj + (size_t)(b * Qn + qt * 16 + wave * 4) * Hn;
    float acc2[4] = {0.f, 0.f, 0.f, 0.f};
    float sumw = 0.f;

    for (int ph = 0; ph < 2; ++ph) {
        __syncthreads();
        #pragma unroll
        for (int i = 0; i < 8; ++i) {       // 64k x 32 f4: transpose + combine
            int idx = t + i * 256;
            int k = idx & 63, h4 = idx >> 6;
            size_t off = (size_t)(b * Kn + k0 + k) * Hn + ph * 128 + h4 * 4;
            float4 p0 = *(const float4*)(kpart0 + off);
            float4 p1 = *(const float4*)(kpart1 + off);
            s_kT[h4 * 4 + 0][k] = p0.x + p1.x;
            s_kT[h4 * 4 + 1][k] = p0.y + p1.y;
            s_kT[h4 * 4 + 2][k] = p0.z + p1.z;
            s_kT[h4 * 4 + 3][k] = p0.w + p1.w;
        }
        __syncthreads();
        #pragma unroll 4
        for (int h = 0; h < 128; ++h) {
            const int hg = ph * 128 + h;
            const float kv = s_kT[h][lane];
            const float wvh = wv[hg];       // uniform -> scalar load
            const float q0 = qb[0 * Hn + hg];
            const float q1 = qb[1 * Hn + hg];
            const float q2 = qb[2 * Hn + hg];
            const float q3 = qb[3 * Hn + hg];
            sumw += wvh;
            float r0 = __builtin_amdgcn_rcpf(1.f + exp2f(q0 + kv));
            float r1 = __builtin_amdgcn_rcpf(1.f + exp2f(q1 + kv));
            float r2 = __builtin_amdgcn_rcpf(1.f + exp2f(q2 + kv));
            float r3 = __builtin_amdgcn_rcpf(1.f + exp2f(q3 + kv));
            acc2[0] = fmaf(wvh, r0, acc2[0]);
            acc2[1] = fmaf(wvh, r1, acc2[1]);
            acc2[2] = fmaf(wvh, r2, acc2[2]);
            acc2[3] = fmaf(wvh, r3, acc2[3]);
        }
    }

    const int k = k0 + lane;
    #pragma unroll
    for (int j = 0; j < 4; ++j) {
        float s = sumw - 2.f * acc2[j];
        float e = (k < vlen) ? exp2f(s * LOG2E) : 0.f;
        if (k < vlen)
            escores[(size_t)(b * Qn + qt * 16 + wave * 4 + j) * Kn + k] = e;
        #pragma unroll
        for (int off = 32; off; off >>= 1)
            e += __shfl_xor(e, off, 64);
        if (lane == 0)
            atomicAdd(&rowsum[b * Qn + qt * 16 + wave * 4 + j], e);
    }
}

// ---------------------------------------------------------------------------
// Kernel 3: split-k AV partials. ZERO LDS: e read via wave-uniform loads
// (scalarizable -> SMEM pipe), values coalesced. Masked k contribute 0
// (escores memset). 512 blocks.
// ---------------------------------------------------------------------------
__global__ __launch_bounds__(256) void av_kernel(
    const float* __restrict__ escores, const float* __restrict__ values,
    float* __restrict__ parts)
{
    const int blk = blockIdx.x;         // (((b*16+qt)*2+dh)*4+kc)
    const int kc = blk & 3;
    const int dh = (blk >> 2) & 1;
    const int qt = (blk >> 3) & 15;
    const int b  = blk >> 7;
    const int t = threadIdx.x;
    const int q0 = qt * 8, kb = kc * 256, d = dh * 256 + t;

    const int ebase = __builtin_amdgcn_readfirstlane((b * Qn + q0) * Kn + kb);
    const float* vb = values + ((size_t)b * Kn + kb) * Dn + d;

    float acc[8] = {0.f, 0.f, 0.f, 0.f, 0.f, 0.f, 0.f, 0.f};
    #pragma unroll 2
    for (int k = 0; k < 256; k += 4) {
        float v0 = vb[(size_t)(k + 0) * Dn];
        float v1 = vb[(size_t)(k + 1) * Dn];
        float v2 = vb[(size_t)(k + 2) * Dn];
        float v3 = vb[(size_t)(k + 3) * Dn];
        #pragma unroll
        for (int j = 0; j < 8; ++j) {
            float4 e4 = *(const float4*)(escores + ebase + j * Kn + k);
            acc[j] += e4.x * v0 + e4.y * v1 + e4.z * v2 + e4.w * v3;
        }
    }
    float* pp = parts + (size_t)kc * (Bn * Qn * Dn) + (size_t)(b * Qn + q0) * Dn + d;
    #pragma unroll
    for (int j = 0; j < 8; ++j)
        pp[(size_t)j * Dn] = acc[j];
}

// ---------------------------------------------------------------------------
// Kernel 4: out = (sum of 4 partials) * rcp(rowsum[row]).
// ---------------------------------------------------------------------------
__global__ __launch_bounds__(256) void reduce_kernel(
    const float* __restrict__ parts, const float* __restrict__ rowsum,
    float* __restrict__ out)
{
    const int idx = blockIdx.x * 256 + threadIdx.x;   // float4 index, 65536 total
    const int row = (idx * 4) >> 9;                   // / Dn
    const float inv = __builtin_amdgcn_rcpf(rowsum[row]);
    const float4* p = (const float4*)parts;
    float4 a = p[idx];
    float4 b = p[idx + 65536];
    float4 c = p[idx + 131072];
    float4 d = p[idx + 196608];
    float4 o;
    o.x = (a.x + b.x + c.x + d.x) * inv;
    o.y = (a.y + b.y + c.y + d.y) * inv;
    o.z = (a.z + b.z + c.z + d.z) * inv;
    o.w = (a.w + b.w + c.w + d.w) * inv;
    ((float4*)out)[idx] = o;
}

// ---------------------------------------------------------------------------
extern "C" void kernel_launch(void* const* d_in, const int* in_sizes, int n_in,
                              void* d_out, int out_size, void* d_ws, size_t ws_size,
                              hipStream_t stream) {
    const float* queries    = (const float*)d_in[0];
    const float* keys       = (const float*)d_in[1];
    const float* values     = (const float*)d_in[2];
    const int*   valid_lens = (const int*)  d_in[3];
    const float* Wq         = (const float*)d_in[4];
    const float* Wk         = (const float*)d_in[5];
    const float* wv         = (const float*)d_in[6];
    float* out = (float*)d_out;

    float* qproj   = (float*)d_ws;                    //  131072 f (pre-scaled)
    float* kpart0  = qproj + Bn * Qn * Hn;            // 1048576 f
    float* kpart1  = kpart0 + Bn * Kn * Hn;           // 1048576 f
    float* escores = kpart1 + Bn * Kn * Hn;           //  524288 f
    float* rowsum  = escores + Bn * Qn * Kn;          //     512 f
    float* parts   = rowsum + Bn * Qn;                // 1048576 f

    // zero escores + rowsum (contiguous, 2.1 MB)
    hipMemsetAsync(escores, 0, (size_t)(Bn * Qn * Kn + Bn * Qn) * sizeof(float),
                   stream);
    proj_kernel<<<576, 128, 0, stream>>>(queries, keys, Wq, Wk, valid_lens,
                                         qproj, kpart0, kpart1);
    score_kernel<<<512, 256, 0, stream>>>(qproj, kpart0, kpart1, wv,
                                          valid_lens, escores, rowsum);
    av_kernel<<<512, 256, 0, stream>>>(escores, values, parts);
    reduce_kernel<<<256, 256, 0, stream>>>(parts, rowsum, out);
}

// Round 6
// 176.188 us; speedup vs baseline: 1.5493x; 1.5493x over previous
//
#include <hip/hip_runtime.h>

#define Bn 4
#define Qn 128
#define Kn 1024
#define Dn 512   // DQ = DK = DV = 512
#define Hn 256
#define SCALE 2.8853900817779268f   // 2*log2(e): pre-scale proj so tanh uses exp2
#define LOG2E 1.4426950408889634f

typedef __attribute__((ext_vector_type(8))) short short8;   // 8 bf16 = 4 VGPRs
typedef __attribute__((ext_vector_type(4))) float floatx4;  // MFMA C/D

// f32 -> bf16 round-to-nearest-even (inputs are finite normals)
__device__ __forceinline__ unsigned short f2bf(float x) {
    unsigned int u = __float_as_uint(x);
    return (unsigned short)((u + 0x7fffu + ((u >> 16) & 1u)) >> 16);
}

// ---------------------------------------------------------------------------
// Kernel 0: prep. blocks 0..63: LDS-transpose Wq/Wk -> Wt[n][k] bf16 (so the
// MFMA B-operand fragment = 8 contiguous bf16 of a Wt row). blocks 64..639:
// straight f32->bf16 convert of queries|keys into qk16[4608][512].
// ---------------------------------------------------------------------------
__global__ __launch_bounds__(256) void prep_kernel(
    const float* __restrict__ queries, const float* __restrict__ keys,
    const float* __restrict__ Wq, const float* __restrict__ Wk,
    unsigned short* __restrict__ qk16,
    unsigned short* __restrict__ wtq, unsigned short* __restrict__ wtk)
{
    const int blk = blockIdx.x;
    const int t = threadIdx.x;
    if (blk < 64) {
        __shared__ float s_t[64][68];
        const int wsel = blk >> 5;
        const int tile = blk & 31;
        const int r0 = (tile >> 2) * 64;    // k-offset (512/64 = 8)
        const int c0 = (tile & 3) * 64;     // n-offset (256/64 = 4)
        const float* W = wsel ? Wk : Wq;
        unsigned short* Wt = wsel ? wtk : wtq;
        #pragma unroll
        for (int i = 0; i < 4; ++i) {
            int idx = t + i * 256;
            int row = idx >> 4, c4 = idx & 15;
            float4 v = *(const float4*)(W + (size_t)(r0 + row) * Hn + c0 + c4 * 4);
            s_t[row][c4*4+0] = v.x; s_t[row][c4*4+1] = v.y;
            s_t[row][c4*4+2] = v.z; s_t[row][c4*4+3] = v.w;
        }
        __syncthreads();
        const int n = c0 + (t >> 2);        // output Wt row
        const int seg = t & 3;              // 16-k segment
        unsigned short tmp[16];
        #pragma unroll
        for (int i = 0; i < 16; ++i)
            tmp[i] = f2bf(s_t[seg * 16 + i][t >> 2]);
        uint4* dst = (uint4*)(Wt + (size_t)n * Dn + r0 + seg * 16);
        dst[0] = ((uint4*)tmp)[0];
        dst[1] = ((uint4*)tmp)[1];
    } else {
        const int cblk = blk - 64;          // 576 blocks x 4096 floats
        const float* src = (cblk < 64) ? (queries + (size_t)cblk * 4096)
                                       : (keys + (size_t)(cblk - 64) * 4096);
        const float* s = src + t * 16;
        unsigned short tmp[16];
        #pragma unroll
        for (int i = 0; i < 4; ++i) {
            float4 v = *(const float4*)(s + i * 4);
            tmp[i*4+0] = f2bf(v.x); tmp[i*4+1] = f2bf(v.y);
            tmp[i*4+2] = f2bf(v.z); tmp[i*4+3] = f2bf(v.w);
        }
        uint4* dst = (uint4*)(qk16 + (size_t)cblk * 4096 + t * 16);
        dst[0] = ((uint4*)tmp)[0];
        dst[1] = ((uint4*)tmp)[1];
    }
}

// ---------------------------------------------------------------------------
// Kernel 1: projections via bf16 MFMA (fp32 acc). Block = 64m x 64n, BK=64,
// 4 waves (wave w owns rows w*16..w*16+15, all 64 n). LDS is stored in exact
// fragment order (slot = (top*2+kc)*64 + lane, 16B) -> stage ds_write_b128 and
// read ds_read_b128 both conflict-free. A-frag: A[m=l&15][k=(l>>4)*8+j];
// B-frag from Wt rows (B^T layout). C/D: col=l&15, row=(l>>4)*4+reg.
// Epilogue scales by 2*log2(e) and stores fp32.
// ---------------------------------------------------------------------------
__global__ __launch_bounds__(256) void proj_mfma_kernel(
    const unsigned short* __restrict__ qk16,
    const unsigned short* __restrict__ wtq,
    const unsigned short* __restrict__ wtk,
    const int* __restrict__ valid_lens,
    float* __restrict__ qproj, float* __restrict__ kproj)
{
    const int blk = blockIdx.x;             // mt(72) * 4 + nt
    const int nt = blk & 3;
    const int mt = blk >> 2;
    const int n0 = nt * 64;
    int arow0, drow0; const unsigned short* Wt; float* Dst;
    if (mt < 8) {
        arow0 = mt * 64; drow0 = arow0; Wt = wtq; Dst = qproj;
    } else {
        int r0 = (mt - 8) * 64;
        if ((r0 & 1023) >= valid_lens[r0 >> 10]) return;  // tile fully masked
        arow0 = 512 + r0; drow0 = r0; Wt = wtk; Dst = kproj;
    }
    const int t = threadIdx.x;
    const int lane = t & 63;
    const int w = t >> 6;

    __shared__ short8 s_a[512];             // 8 KB
    __shared__ short8 s_b[512];             // 8 KB

    // this thread stages slots t and t+256 of each tile
    int arow[2], brow[2], acol[2];
    #pragma unroll
    for (int i = 0; i < 2; ++i) {
        int s = t + i * 256;
        int grp = s >> 6, l = s & 63;
        int top = grp >> 1, kc = grp & 1;
        arow[i] = arow0 + top * 16 + (l & 15);
        brow[i] = n0 + top * 16 + (l & 15);
        acol[i] = kc * 32 + ((l >> 4) << 3);
    }

    floatx4 z = {0.f, 0.f, 0.f, 0.f};
    floatx4 acc0 = z, acc1 = z, acc2 = z, acc3 = z;

    for (int kt = 0; kt < 8; ++kt) {
        __syncthreads();
        #pragma unroll
        for (int i = 0; i < 2; ++i) {
            s_a[t + i*256] = *(const short8*)(qk16 + (size_t)arow[i] * Dn + kt*64 + acol[i]);
            s_b[t + i*256] = *(const short8*)(Wt   + (size_t)brow[i] * Dn + kt*64 + acol[i]);
        }
        __syncthreads();
        #pragma unroll
        for (int kc = 0; kc < 2; ++kc) {
            short8 a  = s_a[(w*2 + kc)*64 + lane];
            short8 b0 = s_b[(0  + kc)*64 + lane];
            short8 b1 = s_b[(2  + kc)*64 + lane];
            short8 b2 = s_b[(4  + kc)*64 + lane];
            short8 b3 = s_b[(6  + kc)*64 + lane];
            acc0 = __builtin_amdgcn_mfma_f32_16x16x32_bf16(a, b0, acc0, 0, 0, 0);
            acc1 = __builtin_amdgcn_mfma_f32_16x16x32_bf16(a, b1, acc1, 0, 0, 0);
            acc2 = __builtin_amdgcn_mfma_f32_16x16x32_bf16(a, b2, acc2, 0, 0, 0);
            acc3 = __builtin_amdgcn_mfma_f32_16x16x32_bf16(a, b3, acc3, 0, 0, 0);
        }
    }

    const int mrow = drow0 + w * 16 + ((lane >> 4) << 2);
    const int ncol = n0 + (lane & 15);
    float* dp = Dst + (size_t)mrow * Hn + ncol;
    floatx4 av[4] = {acc0, acc1, acc2, acc3};
    #pragma unroll
    for (int g = 0; g < 4; ++g)
        #pragma unroll
        for (int r = 0; r < 4; ++r)
            dp[(size_t)r * Hn + g * 16] = av[g][r] * SCALE;
}

// ---------------------------------------------------------------------------
// Kernel 2: e = exp(score), max-free (|score| <= sum|wv|). Block = (b,16q,64k);
// wave = 4 q-rows. k staged transposed s_kT[h][k] (2-way = free b32 reads);
// q-rows + wv via wave-uniform scalar loads (SMEM pipe). tanh via exp2 on
// pre-scaled projections. Per-row expsum: butterfly + one atomic per wave.
// ---------------------------------------------------------------------------
__global__ __launch_bounds__(256) void score_kernel(
    const float* __restrict__ qproj, const float* __restrict__ kproj,
    const float* __restrict__ wv, const int* __restrict__ valid_lens,
    float* __restrict__ escores, float* __restrict__ rowsum)
{
    const int blk = blockIdx.x;             // ((b*8 + qt)*16 + kt)
    const int kt = blk & 15;
    const int qt = (blk >> 4) & 7;
    const int b  = blk >> 7;
    const int vlen = valid_lens[b];
    const int k0 = kt * 64;
    if (k0 >= vlen) return;
    const int t = threadIdx.x;
    const int wave = __builtin_amdgcn_readfirstlane(t >> 6);
    const int lane = t & 63;

    __shared__ float s_kT[128][64];         // 32 KB, one h-half at a time

    const float* qb = qproj + (size_t)(b * Qn + qt * 16 + wave * 4) * Hn;
    float acc2[4] = {0.f, 0.f, 0.f, 0.f};
    float sumw = 0.f;

    for (int ph = 0; ph < 2; ++ph) {
        __syncthreads();
        #pragma unroll
        for (int i = 0; i < 8; ++i) {       // 64k x 32 f4: transpose staging
            int idx = t + i * 256;
            int k = idx & 63, h4 = idx >> 6;
            size_t off = (size_t)(b * Kn + k0 + k) * Hn + ph * 128 + h4 * 4;
            float4 p0 = *(const float4*)(kproj + off);
            s_kT[h4 * 4 + 0][k] = p0.x;
            s_kT[h4 * 4 + 1][k] = p0.y;
            s_kT[h4 * 4 + 2][k] = p0.z;
            s_kT[h4 * 4 + 3][k] = p0.w;
        }
        __syncthreads();
        #pragma unroll 4
        for (int h = 0; h < 128; ++h) {
            const int hg = ph * 128 + h;
            const float kv = s_kT[h][lane];
            const float wvh = wv[hg];       // uniform -> scalar load
            const float q0 = qb[0 * Hn + hg];
            const float q1 = qb[1 * Hn + hg];
            const float q2 = qb[2 * Hn + hg];
            const float q3 = qb[3 * Hn + hg];
            sumw += wvh;
            float r0 = __builtin_amdgcn_rcpf(1.f + exp2f(q0 + kv));
            float r1 = __builtin_amdgcn_rcpf(1.f + exp2f(q1 + kv));
            float r2 = __builtin_amdgcn_rcpf(1.f + exp2f(q2 + kv));
            float r3 = __builtin_amdgcn_rcpf(1.f + exp2f(q3 + kv));
            acc2[0] = fmaf(wvh, r0, acc2[0]);
            acc2[1] = fmaf(wvh, r1, acc2[1]);
            acc2[2] = fmaf(wvh, r2, acc2[2]);
            acc2[3] = fmaf(wvh, r3, acc2[3]);
        }
    }

    const int k = k0 + lane;
    #pragma unroll
    for (int j = 0; j < 4; ++j) {
        float s = sumw - 2.f * acc2[j];     // score = sum(wv) - 2*sum(wv*rcp)
        float e = (k < vlen) ? exp2f(s * LOG2E) : 0.f;
        if (k < vlen)
            escores[(size_t)(b * Qn + qt * 16 + wave * 4 + j) * Kn + k] = e;
        #pragma unroll
        for (int off = 32; off; off >>= 1)
            e += __shfl_xor(e, off, 64);
        if (lane == 0)
            atomicAdd(&rowsum[b * Qn + qt * 16 + wave * 4 + j], e);
    }
}

// ---------------------------------------------------------------------------
// Kernel 3: split-k AV partials. Zero LDS: e-rows via wave-uniform loads,
// values coalesced. Masked k contribute 0 (escores memset). 512 blocks.
// ---------------------------------------------------------------------------
__global__ __launch_bounds__(256) void av_kernel(
    const float* __restrict__ escores, const float* __restrict__ values,
    float* __restrict__ parts)
{
    const int blk = blockIdx.x;         // (((b*16+qt)*2+dh)*4+kc)
    const int kc = blk & 3;
    const int dh = (blk >> 2) & 1;
    const int qt = (blk >> 3) & 15;
    const int b  = blk >> 7;
    const int t = threadIdx.x;
    const int q0 = qt * 8, kb = kc * 256, d = dh * 256 + t;

    const int ebase = __builtin_amdgcn_readfirstlane((b * Qn + q0) * Kn + kb);
    const float* vb = values + ((size_t)b * Kn + kb) * Dn + d;

    float acc[8] = {0.f, 0.f, 0.f, 0.f, 0.f, 0.f, 0.f, 0.f};
    #pragma unroll 2
    for (int k = 0; k < 256; k += 4) {
        float v0 = vb[(size_t)(k + 0) * Dn];
        float v1 = vb[(size_t)(k + 1) * Dn];
        float v2 = vb[(size_t)(k + 2) * Dn];
        float v3 = vb[(size_t)(k + 3) * Dn];
        #pragma unroll
        for (int j = 0; j < 8; ++j) {
            float4 e4 = *(const float4*)(escores + ebase + j * Kn + k);
            acc[j] += e4.x * v0 + e4.y * v1 + e4.z * v2 + e4.w * v3;
        }
    }
    float* pp = parts + (size_t)kc * (Bn * Qn * Dn) + (size_t)(b * Qn + q0) * Dn + d;
    #pragma unroll
    for (int j = 0; j < 8; ++j)
        pp[(size_t)j * Dn] = acc[j];
}

// ---------------------------------------------------------------------------
// Kernel 4: out = (sum of 4 partials) * rcp(rowsum[row]).
// ---------------------------------------------------------------------------
__global__ __launch_bounds__(256) void reduce_kernel(
    const float* __restrict__ parts, const float* __restrict__ rowsum,
    float* __restrict__ out)
{
    const int idx = blockIdx.x * 256 + threadIdx.x;   // float4 index, 65536
    const int row = (idx * 4) >> 9;                   // / Dn
    const float inv = __builtin_amdgcn_rcpf(rowsum[row]);
    const float4* p = (const float4*)parts;
    float4 a = p[idx];
    float4 b = p[idx + 65536];
    float4 c = p[idx + 131072];
    float4 d = p[idx + 196608];
    float4 o;
    o.x = (a.x + b.x + c.x + d.x) * inv;
    o.y = (a.y + b.y + c.y + d.y) * inv;
    o.z = (a.z + b.z + c.z + d.z) * inv;
    o.w = (a.w + b.w + c.w + d.w) * inv;
    ((float4*)out)[idx] = o;
}

// ---------------------------------------------------------------------------
extern "C" void kernel_launch(void* const* d_in, const int* in_sizes, int n_in,
                              void* d_out, int out_size, void* d_ws, size_t ws_size,
                              hipStream_t stream) {
    const float* queries    = (const float*)d_in[0];
    const float* keys       = (const float*)d_in[1];
    const float* values     = (const float*)d_in[2];
    const int*   valid_lens = (const int*)  d_in[3];
    const float* Wq         = (const float*)d_in[4];
    const float* Wk         = (const float*)d_in[5];
    const float* wv         = (const float*)d_in[6];
    float* out = (float*)d_out;

    float* qproj   = (float*)d_ws;                    //  131072 f (pre-scaled)
    float* kproj   = qproj + Bn * Qn * Hn;            // 1048576 f (pre-scaled)
    float* escores = kproj + Bn * Kn * Hn;            //  524288 f
    float* rowsum  = escores + Bn * Qn * Kn;          //     512 f
    float* parts   = rowsum + Bn * Qn;                // 1048576 f
    unsigned short* qk16 = (unsigned short*)(parts + 4 * Bn * Qn * Dn);
    unsigned short* wtq  = qk16 + 4608 * 512;         // Wt_q [256][512] bf16
    unsigned short* wtk  = wtq + 256 * 512;           // Wt_k [256][512] bf16

    hipMemsetAsync(escores, 0, (size_t)(Bn * Qn * Kn + Bn * Qn) * sizeof(float),
                   stream);
    prep_kernel<<<640, 256, 0, stream>>>(queries, keys, Wq, Wk, qk16, wtq, wtk);
    proj_mfma_kernel<<<288, 256, 0, stream>>>(qk16, wtq, wtk, valid_lens,
                                              qproj, kproj);
    score_kernel<<<512, 256, 0, stream>>>(qproj, kproj, wv, valid_lens,
                                          escores, rowsum);
    av_kernel<<<512, 256, 0, stream>>>(escores, values, parts);
    reduce_kernel<<<256, 256, 0, stream>>>(parts, rowsum, out);
}

// Round 7
// 174.391 us; speedup vs baseline: 1.5652x; 1.0103x over previous
//
#include <hip/hip_runtime.h>

#define Bn 4
#define Qn 128
#define Kn 1024
#define Dn 512   // DQ = DK = DV = 512
#define Hn 256
#define SCALE 2.8853900817779268f   // 2*log2(e): pre-scale proj so tanh uses exp2
#define LOG2E 1.4426950408889634f

typedef __attribute__((ext_vector_type(8))) short short8;   // 8 bf16 = 4 VGPRs
typedef __attribute__((ext_vector_type(4))) float floatx4;  // MFMA C/D

// f32 -> bf16 round-to-nearest-even (inputs are finite normals)
__device__ __forceinline__ unsigned short f2bf(float x) {
    unsigned int u = __float_as_uint(x);
    return (unsigned short)((u + 0x7fffu + ((u >> 16) & 1u)) >> 16);
}

// ---------------------------------------------------------------------------
// Kernel 0: prep. blocks 0..63: LDS-transpose Wq/Wk -> Wt[n][k] bf16 (MFMA
// B-operand = 8 contiguous bf16 of a Wt row). blocks 64..639: f32->bf16
// convert of queries|keys into qk16[4608][512].
// ---------------------------------------------------------------------------
__global__ __launch_bounds__(256) void prep_kernel(
    const float* __restrict__ queries, const float* __restrict__ keys,
    const float* __restrict__ Wq, const float* __restrict__ Wk,
    unsigned short* __restrict__ qk16,
    unsigned short* __restrict__ wtq, unsigned short* __restrict__ wtk)
{
    const int blk = blockIdx.x;
    const int t = threadIdx.x;
    if (blk < 64) {
        __shared__ float s_t[64][68];
        const int wsel = blk >> 5;
        const int tile = blk & 31;
        const int r0 = (tile >> 2) * 64;    // k-offset (512/64 = 8)
        const int c0 = (tile & 3) * 64;     // n-offset (256/64 = 4)
        const float* W = wsel ? Wk : Wq;
        unsigned short* Wt = wsel ? wtk : wtq;
        #pragma unroll
        for (int i = 0; i < 4; ++i) {
            int idx = t + i * 256;
            int row = idx >> 4, c4 = idx & 15;
            float4 v = *(const float4*)(W + (size_t)(r0 + row) * Hn + c0 + c4 * 4);
            s_t[row][c4*4+0] = v.x; s_t[row][c4*4+1] = v.y;
            s_t[row][c4*4+2] = v.z; s_t[row][c4*4+3] = v.w;
        }
        __syncthreads();
        const int n = c0 + (t >> 2);        // output Wt row
        const int seg = t & 3;              // 16-k segment
        unsigned short tmp[16];
        #pragma unroll
        for (int i = 0; i < 16; ++i)
            tmp[i] = f2bf(s_t[seg * 16 + i][t >> 2]);
        uint4* dst = (uint4*)(Wt + (size_t)n * Dn + r0 + seg * 16);
        dst[0] = ((uint4*)tmp)[0];
        dst[1] = ((uint4*)tmp)[1];
    } else {
        const int cblk = blk - 64;          // 576 blocks x 4096 floats
        const float* src = (cblk < 64) ? (queries + (size_t)cblk * 4096)
                                       : (keys + (size_t)(cblk - 64) * 4096);
        const float* s = src + t * 16;
        unsigned short tmp[16];
        #pragma unroll
        for (int i = 0; i < 4; ++i) {
            float4 v = *(const float4*)(s + i * 4);
            tmp[i*4+0] = f2bf(v.x); tmp[i*4+1] = f2bf(v.y);
            tmp[i*4+2] = f2bf(v.z); tmp[i*4+3] = f2bf(v.w);
        }
        uint4* dst = (uint4*)(qk16 + (size_t)cblk * 4096 + t * 16);
        dst[0] = ((uint4*)tmp)[0];
        dst[1] = ((uint4*)tmp)[1];
    }
}

// ---------------------------------------------------------------------------
// Kernel 1: projections via bf16 MFMA (fp32 acc). Block = 64m x 64n, BK=64.
// q-type writes qproj[row][h] directly (score reads it scalar).
// k-type transposes its 64x64 tile in LDS (reusing the staging buffer) and
// writes kprojT[b][h][k] coalesced -- score streams it with lane=k.
// Both outputs pre-scaled by 2*log2(e).
// ---------------------------------------------------------------------------
__global__ __launch_bounds__(256) void proj_mfma_kernel(
    const unsigned short* __restrict__ qk16,
    const unsigned short* __restrict__ wtq,
    const unsigned short* __restrict__ wtk,
    const int* __restrict__ valid_lens,
    float* __restrict__ qproj, float* __restrict__ kprojT)
{
    const int blk = blockIdx.x;             // mt(72) * 4 + nt
    const int nt = blk & 3;
    const int mt = blk >> 2;
    const int n0 = nt * 64;
    int arow0, drow0; const unsigned short* Wt; bool is_q;
    if (mt < 8) {
        arow0 = mt * 64; drow0 = arow0; Wt = wtq; is_q = true;
    } else {
        int r0 = (mt - 8) * 64;
        if ((r0 & 1023) >= valid_lens[r0 >> 10]) return;  // tile fully masked
        arow0 = 512 + r0; drow0 = r0; Wt = wtk; is_q = false;
    }
    const int t = threadIdx.x;
    const int lane = t & 63;
    const int w = t >> 6;

    __shared__ float s_x[64 * 68];          // 17408 B; aliased by staging bufs
    short8* s_a = (short8*)s_x;             // [512] = 8 KB
    short8* s_b = (short8*)(s_x + 2048);    // [512] = 8 KB

    // this thread stages slots t and t+256 of each tile
    int arow[2], brow[2], acol[2];
    #pragma unroll
    for (int i = 0; i < 2; ++i) {
        int s = t + i * 256;
        int grp = s >> 6, l = s & 63;
        int top = grp >> 1, kc = grp & 1;
        arow[i] = arow0 + top * 16 + (l & 15);
        brow[i] = n0 + top * 16 + (l & 15);
        acol[i] = kc * 32 + ((l >> 4) << 3);
    }

    floatx4 z = {0.f, 0.f, 0.f, 0.f};
    floatx4 acc0 = z, acc1 = z, acc2 = z, acc3 = z;

    for (int kt = 0; kt < 8; ++kt) {
        __syncthreads();
        #pragma unroll
        for (int i = 0; i < 2; ++i) {
            s_a[t + i*256] = *(const short8*)(qk16 + (size_t)arow[i] * Dn + kt*64 + acol[i]);
            s_b[t + i*256] = *(const short8*)(Wt   + (size_t)brow[i] * Dn + kt*64 + acol[i]);
        }
        __syncthreads();
        #pragma unroll
        for (int kc = 0; kc < 2; ++kc) {
            short8 a  = s_a[(w*2 + kc)*64 + lane];
            short8 b0 = s_b[(0  + kc)*64 + lane];
            short8 b1 = s_b[(2  + kc)*64 + lane];
            short8 b2 = s_b[(4  + kc)*64 + lane];
            short8 b3 = s_b[(6  + kc)*64 + lane];
            acc0 = __builtin_amdgcn_mfma_f32_16x16x32_bf16(a, b0, acc0, 0, 0, 0);
            acc1 = __builtin_amdgcn_mfma_f32_16x16x32_bf16(a, b1, acc1, 0, 0, 0);
            acc2 = __builtin_amdgcn_mfma_f32_16x16x32_bf16(a, b2, acc2, 0, 0, 0);
            acc3 = __builtin_amdgcn_mfma_f32_16x16x32_bf16(a, b3, acc3, 0, 0, 0);
        }
    }

    floatx4 av[4] = {acc0, acc1, acc2, acc3};
    if (is_q) {
        const int mrow = drow0 + w * 16 + ((lane >> 4) << 2);
        const int ncol = n0 + (lane & 15);
        float* dp = qproj + (size_t)mrow * Hn + ncol;
        #pragma unroll
        for (int g = 0; g < 4; ++g)
            #pragma unroll
            for (int r = 0; r < 4; ++r)
                dp[(size_t)r * Hn + g * 16] = av[g][r] * SCALE;
    } else {
        __syncthreads();                    // staging bufs dead; reuse as s_x
        #pragma unroll
        for (int g = 0; g < 4; ++g) {
            const int n_loc = g * 16 + (lane & 15);
            const int m_base = w * 16 + ((lane >> 4) << 2);
            #pragma unroll
            for (int r = 0; r < 4; ++r)
                s_x[n_loc * 68 + m_base + r] = av[g][r] * SCALE;
        }
        __syncthreads();
        const int bq = drow0 >> 10;
        const int kk0 = drow0 & 1023;
        float* dstT = kprojT + ((size_t)bq * Hn + n0) * Kn + kk0;
        #pragma unroll
        for (int i = 0; i < 4; ++i) {       // 64 h-rows x 16 float4
            int f4 = t + i * 256;
            int row = f4 >> 4, c4 = f4 & 15;
            *(float4*)(dstT + (size_t)row * Kn + c4 * 4) =
                *(const float4*)&s_x[row * 68 + c4 * 4];
        }
    }
}

// ---------------------------------------------------------------------------
// Kernel 2: e = exp(score), max-free. ZERO LDS. Block = 4 q-rows x 64 k;
// wave = 1 q-row, lane = 1 k-column. kprojT streamed coalesced (b32, lane=k);
// q-row + wv wave-uniform scalar loads. tanh via exp2 on pre-scaled proj.
// Grid 2048 (~4 active blocks/CU after mask-skip).
// ---------------------------------------------------------------------------
__global__ __launch_bounds__(256) void score_kernel(
    const float* __restrict__ qproj, const float* __restrict__ kprojT,
    const float* __restrict__ wv, const int* __restrict__ valid_lens,
    float* __restrict__ escores, float* __restrict__ rowsum)
{
    const int blk = blockIdx.x;             // ((b*32 + qt)*16 + kt)
    const int kt = blk & 15;
    const int qt = (blk >> 4) & 31;
    const int b  = blk >> 9;
    const int vlen = valid_lens[b];
    const int k0 = kt * 64;
    if (k0 >= vlen) return;
    const int t = threadIdx.x;
    const int wave = __builtin_amdgcn_readfirstlane(t >> 6);
    const int lane = t & 63;
    const int qrow = qt * 4 + wave;

    const float* qb = qproj + (size_t)(b * Qn + qrow) * Hn;
    const float* kb = kprojT + (size_t)b * Hn * Kn + k0 + lane;

    // sum(wv) once per wave (identical in all lanes after butterfly)
    float sumw = wv[lane] + wv[lane + 64] + wv[lane + 128] + wv[lane + 192];
    #pragma unroll
    for (int off = 32; off; off >>= 1)
        sumw += __shfl_xor(sumw, off, 64);

    float acc = 0.f;
    #pragma unroll 8
    for (int h = 0; h < Hn; ++h) {
        float kv = kb[(size_t)h * Kn];      // coalesced b32 stream
        float qv = qb[h];                   // uniform -> s_load
        float wvh = wv[h];                  // uniform -> s_load
        acc = fmaf(wvh, __builtin_amdgcn_rcpf(1.f + exp2f(qv + kv)), acc);
    }
    float s = sumw - 2.f * acc;             // = sum_h wv*tanh(q+k)

    const int k = k0 + lane;
    float e = (k < vlen) ? exp2f(s * LOG2E) : 0.f;
    if (k < vlen)
        escores[(size_t)(b * Qn + qrow) * Kn + k] = e;
    #pragma unroll
    for (int off = 32; off; off >>= 1)
        e += __shfl_xor(e, off, 64);
    if (lane == 0)
        atomicAdd(&rowsum[b * Qn + qrow], e);
}

// ---------------------------------------------------------------------------
// Kernel 3: split-k AV partials. Zero LDS: e-rows via wave-uniform loads,
// values coalesced. Masked k contribute 0 (escores memset). 512 blocks.
// ---------------------------------------------------------------------------
__global__ __launch_bounds__(256) void av_kernel(
    const float* __restrict__ escores, const float* __restrict__ values,
    float* __restrict__ parts)
{
    const int blk = blockIdx.x;         // (((b*16+qt)*2+dh)*4+kc)
    const int kc = blk & 3;
    const int dh = (blk >> 2) & 1;
    const int qt = (blk >> 3) & 15;
    const int b  = blk >> 7;
    const int t = threadIdx.x;
    const int q0 = qt * 8, kb = kc * 256, d = dh * 256 + t;

    const int ebase = __builtin_amdgcn_readfirstlane((b * Qn + q0) * Kn + kb);
    const float* vb = values + ((size_t)b * Kn + kb) * Dn + d;

    float acc[8] = {0.f, 0.f, 0.f, 0.f, 0.f, 0.f, 0.f, 0.f};
    #pragma unroll 2
    for (int k = 0; k < 256; k += 4) {
        float v0 = vb[(size_t)(k + 0) * Dn];
        float v1 = vb[(size_t)(k + 1) * Dn];
        float v2 = vb[(size_t)(k + 2) * Dn];
        float v3 = vb[(size_t)(k + 3) * Dn];
        #pragma unroll
        for (int j = 0; j < 8; ++j) {
            float4 e4 = *(const float4*)(escores + ebase + j * Kn + k);
            acc[j] += e4.x * v0 + e4.y * v1 + e4.z * v2 + e4.w * v3;
        }
    }
    float* pp = parts + (size_t)kc * (Bn * Qn * Dn) + (size_t)(b * Qn + q0) * Dn + d;
    #pragma unroll
    for (int j = 0; j < 8; ++j)
        pp[(size_t)j * Dn] = acc[j];
}

// ---------------------------------------------------------------------------
// Kernel 4: out = (sum of 4 partials) * rcp(rowsum[row]).
// ---------------------------------------------------------------------------
__global__ __launch_bounds__(256) void reduce_kernel(
    const float* __restrict__ parts, const float* __restrict__ rowsum,
    float* __restrict__ out)
{
    const int idx = blockIdx.x * 256 + threadIdx.x;   // float4 index, 65536
    const int row = (idx * 4) >> 9;                   // / Dn
    const float inv = __builtin_amdgcn_rcpf(rowsum[row]);
    const float4* p = (const float4*)parts;
    float4 a = p[idx];
    float4 b = p[idx + 65536];
    float4 c = p[idx + 131072];
    float4 d = p[idx + 196608];
    float4 o;
    o.x = (a.x + b.x + c.x + d.x) * inv;
    o.y = (a.y + b.y + c.y + d.y) * inv;
    o.z = (a.z + b.z + c.z + d.z) * inv;
    o.w = (a.w + b.w + c.w + d.w) * inv;
    ((float4*)out)[idx] = o;
}

// ---------------------------------------------------------------------------
extern "C" void kernel_launch(void* const* d_in, const int* in_sizes, int n_in,
                              void* d_out, int out_size, void* d_ws, size_t ws_size,
                              hipStream_t stream) {
    const float* queries    = (const float*)d_in[0];
    const float* keys       = (const float*)d_in[1];
    const float* values     = (const float*)d_in[2];
    const int*   valid_lens = (const int*)  d_in[3];
    const float* Wq         = (const float*)d_in[4];
    const float* Wk         = (const float*)d_in[5];
    const float* wv         = (const float*)d_in[6];
    float* out = (float*)d_out;

    float* qproj   = (float*)d_ws;                    //  131072 f (pre-scaled)
    float* kprojT  = qproj + Bn * Qn * Hn;            // 1048576 f [B][H][K]
    float* escores = kprojT + Bn * Hn * Kn;           //  524288 f
    float* rowsum  = escores + Bn * Qn * Kn;          //     512 f
    float* parts   = rowsum + Bn * Qn;                // 1048576 f
    unsigned short* qk16 = (unsigned short*)(parts + 4 * Bn * Qn * Dn);
    unsigned short* wtq  = qk16 + 4608 * 512;         // Wt_q [256][512] bf16
    unsigned short* wtk  = wtq + 256 * 512;           // Wt_k [256][512] bf16

    hipMemsetAsync(escores, 0, (size_t)(Bn * Qn * Kn + Bn * Qn) * sizeof(float),
                   stream);
    prep_kernel<<<640, 256, 0, stream>>>(queries, keys, Wq, Wk, qk16, wtq, wtk);
    proj_mfma_kernel<<<288, 256, 0, stream>>>(qk16, wtq, wtk, valid_lens,
                                              qproj, kprojT);
    score_kernel<<<2048, 256, 0, stream>>>(qproj, kprojT, wv, valid_lens,
                                           escores, rowsum);
    av_kernel<<<512, 256, 0, stream>>>(escores, values, parts);
    reduce_kernel<<<256, 256, 0, stream>>>(parts, rowsum, out);
}